// Round 11
// baseline (32672.995 us; speedup 1.0000x reference)
//
#include <hip/hip_runtime.h>

#define TLEN 2048
#define NB   64
#define NH   256
#define NF   64
#define NCIN 16
#define NOUT 20
#define NG   8              // batch groups (sync domains)
#define GS   8              // samples per group
#define SLU  16             // hidden units per slice (block)
#define GSLAB (NH * GS)     // 2048 floats: one group's h slab [unit][sample]
#define NSLOT 8             // h ring depth

// LLC-coherent (sc1) access helpers.
#define HL(p)    __hip_atomic_load((p),      __ATOMIC_RELAXED, __HIP_MEMORY_SCOPE_AGENT)
#define HS(p, v) __hip_atomic_store((p), (v), __ATOMIC_RELAXED, __HIP_MEMORY_SCOPE_AGENT)

__device__ __forceinline__ float poison_f() { return __uint_as_float(0xFFFFFFFFu); }

__device__ __forceinline__ float sigf(float x) { return 1.0f / (1.0f + __expf(-x)); }
__device__ __forceinline__ float tanh_f(float x) {
    x = fminf(fmaxf(x, -15.0f), 15.0f);
    float e = __expf(2.0f * x);
    return (e - 1.0f) / (e + 1.0f);
}

// NOTE: parameter must NOT be named `w` — `xv.w` would get macro-substituted.
#define FMA4(acc, xv, ww) do { \
    acc.x = fmaf(xv.x, (ww), acc.x); \
    acc.y = fmaf(xv.y, (ww), acc.y); \
    acc.z = fmaf(xv.z, (ww), acc.z); \
    acc.w = fmaf(xv.w, (ww), acc.w); } while (0)

#define RED32(vv) do { \
    vv.x += __shfl_xor(vv.x, 32); vv.y += __shfl_xor(vv.y, 32); \
    vv.z += __shfl_xor(vv.z, 32); vv.w += __shfl_xor(vv.w, 32); } while (0)

// ---------------- Pass A: conv + relu, per-(f, t-quarter) partial sums for BN stats
__global__ __launch_bounds__(256) void conv_stats_kernel(
    const float* __restrict__ x, const float* __restrict__ cw, const float* __restrict__ cb,
    float* __restrict__ partials)
{
    const int blk = blockIdx.x;          // 256 blocks
    const int f = blk >> 2, tq = blk & 3;
    const int tid = threadIdx.x;

    float w[NCIN][3];
#pragma unroll
    for (int c = 0; c < NCIN; ++c) {
        w[c][0] = cw[(f * NCIN + c) * 3 + 0];
        w[c][1] = cw[(f * NCIN + c) * 3 + 1];
        w[c][2] = cw[(f * NCIN + c) * 3 + 2];
    }
    const float bias = cb[f];
    float s = 0.f, s2 = 0.f;

    for (int i = 0; i < 128; ++i) {
        int idx = tq * 32768 + i * 256 + tid;   // (B*T)/4 elements per block
        int b = idx >> 11;
        int t = idx & 2047;
        const float* xb = x + (size_t)b * NCIN * TLEN;
        float acc = bias;
#pragma unroll
        for (int c = 0; c < NCIN; ++c) {
            const float* xc = xb + (size_t)c * TLEN + t;
            float xm = (t > 0)        ? xc[-1] : 0.f;
            float x0 = xc[0];
            float xp = (t < TLEN - 1) ? xc[1]  : 0.f;
            acc = fmaf(xm, w[c][0], acc);
            acc = fmaf(x0, w[c][1], acc);
            acc = fmaf(xp, w[c][2], acc);
        }
        float y = fmaxf(acc, 0.f);
        s += y; s2 = fmaf(y, y, s2);
    }

    __shared__ float rs[256], rs2[256];
    rs[tid] = s; rs2[tid] = s2;
    __syncthreads();
    for (int off = 128; off > 0; off >>= 1) {
        if (tid < off) { rs[tid] += rs[tid + off]; rs2[tid] += rs2[tid + off]; }
        __syncthreads();
    }
    if (tid == 0) {
        partials[(f * 4 + tq) * 2 + 0] = rs[0];
        partials[(f * 4 + tq) * 2 + 1] = rs2[0];
    }
}

// ---------------- Pass B: conv + relu + BN affine, write feats[t][g][f][bl]
__global__ __launch_bounds__(256) void conv_bn_feats_kernel(
    const float* __restrict__ x, const float* __restrict__ cw, const float* __restrict__ cb,
    const float* __restrict__ gamma, const float* __restrict__ beta,
    const float* __restrict__ partials, float* __restrict__ feats)
{
    const int t = blockIdx.x;            // 2048 blocks
    const int tid = threadIdx.x;
    const int b = tid & 63, fq = tid >> 6;

    __shared__ float sc[NF], sh[NF];
    if (tid < NF) {
        int f = tid;
        float s = 0.f, s2 = 0.f;
        for (int q = 0; q < 4; ++q) {
            s  += partials[(f * 4 + q) * 2 + 0];
            s2 += partials[(f * 4 + q) * 2 + 1];
        }
        const float inv_n = 1.0f / ((float)NB * (float)TLEN);
        float mean = s * inv_n;
        float var  = s2 * inv_n - mean * mean;
        float iv   = rsqrtf(var + 1e-5f);
        float scale = gamma[f] * iv;
        sc[f] = scale;
        sh[f] = beta[f] - mean * scale;
    }
    __syncthreads();

    float xr[NCIN][3];
    const float* xb = x + (size_t)b * NCIN * TLEN;
#pragma unroll
    for (int c = 0; c < NCIN; ++c) {
        const float* xc = xb + (size_t)c * TLEN + t;
        xr[c][0] = (t > 0)        ? xc[-1] : 0.f;
        xr[c][1] = xc[0];
        xr[c][2] = (t < TLEN - 1) ? xc[1]  : 0.f;
    }

    float* ft = feats + (size_t)t * (NG * NF * GS);
    for (int fi = 0; fi < 16; ++fi) {
        int f = fq * 16 + fi;
        float acc = cb[f];
#pragma unroll
        for (int c = 0; c < NCIN; ++c) {
            acc = fmaf(xr[c][0], cw[(f * NCIN + c) * 3 + 0], acc);
            acc = fmaf(xr[c][1], cw[(f * NCIN + c) * 3 + 1], acc);
            acc = fmaf(xr[c][2], cw[(f * NCIN + c) * 3 + 2], acc);
        }
        float y = fmaxf(acc, 0.f);
        ft[((b >> 3) * NF + f) * GS + (b & 7)] = fmaf(y, sc[f], sh[f]);
    }
}

// =====================================================================
// NaN-poison protocol (unchanged from r10) + split-K phase scheduling:
//   Phase A stages/computes the READY half (L1: h0[s], lag-buffered; L0: feats),
//   Phase B then NaN-waits on the recurrent half (h1[s-1] / peer h0[s-1]),
//   so the peer-wait overlaps phase-A compute of the same step.
//   - h[m] lives in slot (m+1)&7; producer writes value, consumer retries on NaN
//   - producer at step s re-poisons slot (s+5)&7 (holds h[s-4])
//   - L0 poison guard: sentinel h1[s-3] present => all L1 done with h0[s-4]
// =====================================================================

// ---------------- layer-0 block (slice sl of group g)
__device__ __forceinline__ void run_l0(
    int g, int sl, int tid,
    const float* __restrict__ feats,
    const float* __restrict__ wih, const float* __restrict__ whh,
    const float* __restrict__ bih, const float* __restrict__ bhh,
    float* h0, const float* h1,
    float* xs, float* red, float (*biasS)[SLU])
{
    constexpr int KF8 = NF / 8;           // 8  feats ks per thread
    constexpr int KH8 = NH / 8;           // 32 h ks per thread
    const int jp = tid & 7;
    const int g4 = (tid >> 3) & 3;
    const int kq = tid >> 5;
    const int rowA = g4 * 256 + sl * SLU + jp;
    const int rowB = rowA + 8;

    float waF[KF8], wbF[KF8], waH[KH8], wbH[KH8];
#pragma unroll
    for (int kk = 0; kk < KF8; ++kk) {
        int k = kq * KF8 + kk;
        waF[kk] = wih[rowA * NF + k];
        wbF[kk] = wih[rowB * NF + k];
    }
#pragma unroll
    for (int kk = 0; kk < KH8; ++kk) {
        int k = kq * KH8 + kk;
        waH[kk] = whh[rowA * NH + k];
        wbH[kk] = whh[rowB * NH + k];
    }
    if (tid < 64) {
        int gg = tid >> 4, jj = tid & 15, grow = gg * 256 + sl * SLU + jj;
        biasS[gg][jj] = bih[grow] + bhh[grow];
    }
    __syncthreads();

    const int fj = tid >> 3, fb = tid & 7;
    float c_reg = 0.f;
    const int sj = (tid >= 128 && tid < 144) ? tid - 128 : 0;   // sentinel slice id

    for (int s = 0; s < TLEN; ++s) {
        // ---- phase A: feats (no sync needed), stage + GEMM
        const float* fsrc = feats + ((size_t)s * NG + g) * (NF * GS);
        float f0 = fsrc[tid], f1 = fsrc[256 + tid];
        xs[tid] = f0; xs[256 + tid] = f1;
        __syncthreads();

        float4 aA0 = {0,0,0,0}, aA1 = {0,0,0,0}, aB0 = {0,0,0,0}, aB1 = {0,0,0,0};
        {
            const float* xsk = xs + (kq * KF8) * GS;
#pragma unroll
            for (int kk = 0; kk < KF8; ++kk) {
                float4 x0 = *(const float4*)(xsk + kk * GS);
                float4 x1 = *(const float4*)(xsk + kk * GS + 4);
                float wAv = waF[kk], wBv = wbF[kk];
                FMA4(aA0, x0, wAv); FMA4(aA1, x1, wAv);
                FMA4(aB0, x0, wBv); FMA4(aB1, x1, wBv);
            }
        }

        // ---- phase B: NaN-wait on peer h0[s-1] (slot s&7) + sentinel, stage + GEMM
        const float* hp   = h0 + ((size_t)(s & 7) * NG + g) * GSLAB + tid;
        const float* sent = h1 + ((size_t)((s + 6) & 7) * NG + g) * GSLAB + sj * 128;
        float hv[8];
        for (;;) {
            bool bad = false;
#pragma unroll
            for (int i = 0; i < 8; ++i) { hv[i] = HL(hp + i * 256); if (hv[i] != hv[i]) bad = true; }
            if (s >= 3 && tid >= 128 && tid < 144) {
                float sv = HL(sent); if (sv != sv) bad = true;
            }
            if (__syncthreads_count(bad) == 0) break;
            __builtin_amdgcn_s_sleep(2);
        }
#pragma unroll
        for (int i = 0; i < 8; ++i) xs[512 + i * 256 + tid] = hv[i];
        __syncthreads();

        {
            const float* xsk = xs + (NF + kq * KH8) * GS;
#pragma unroll
            for (int kk = 0; kk < KH8; ++kk) {
                float4 x0 = *(const float4*)(xsk + kk * GS);
                float4 x1 = *(const float4*)(xsk + kk * GS + 4);
                float wAv = waH[kk], wBv = wbH[kk];
                FMA4(aA0, x0, wAv); FMA4(aA1, x1, wAv);
                FMA4(aB0, x0, wBv); FMA4(aB1, x1, wBv);
            }
        }
        RED32(aA0); RED32(aA1); RED32(aB0); RED32(aB1);
        if ((tid & 32) == 0) {
            int gk = g4 * 4 + (tid >> 6);
            float4* r4 = (float4*)red;
            r4[gk * 32 + jp * 2 + 0]       = aA0;
            r4[gk * 32 + jp * 2 + 1]       = aA1;
            r4[gk * 32 + (jp + 8) * 2 + 0] = aB0;
            r4[gk * 32 + (jp + 8) * 2 + 1] = aB1;
        }
        __syncthreads();

        if (tid < 128) {
            float gate[4];
#pragma unroll
            for (int gg = 0; gg < 4; ++gg) {
                float s0 = 0.f;
#pragma unroll
                for (int k2 = 0; k2 < 4; ++k2)
                    s0 += red[(gg * 4 + k2) * 128 + fj * 8 + fb];
                gate[gg] = s0 + biasS[gg][fj];
            }
            float i_ = sigf(gate[0]), f_ = sigf(gate[1]);
            float g_ = tanh_f(gate[2]), o_ = sigf(gate[3]);
            c_reg = fmaf(f_, c_reg, i_ * g_);
            float h = o_ * tanh_f(c_reg);
            HS(&h0[((size_t)((s + 1) & 7) * NG + g) * GSLAB + sl * 128 + tid], h);
            // re-poison slot (s+5)&7 (= h0[s-4]); guarded by the sentinel above
            HS(&h0[((size_t)((s + 5) & 7) * NG + g) * GSLAB + sl * 128 + tid], poison_f());
        }
        // next iteration's barriers synchronize xs reuse (phase-A region disjoint)
        __syncthreads();
    }
}

// ---------------- layer-1 block (slice sl of group g), FC fused
__device__ __forceinline__ void run_l1(
    int g, int sl, int tid,
    const float* __restrict__ h0,
    const float* __restrict__ wih, const float* __restrict__ whh,
    const float* __restrict__ bih, const float* __restrict__ bhh,
    const float* __restrict__ fcw, const float* __restrict__ fcb,
    float* h1, float* __restrict__ out,
    float* xs, float* red, float (*biasS)[SLU])
{
    constexpr int KH8 = NH / 8;           // 32 ks per thread per half
    const int jp = tid & 7;
    const int g4 = (tid >> 3) & 3;
    const int kq = tid >> 5;
    const int rowA = g4 * 256 + sl * SLU + jp;
    const int rowB = rowA + 8;

    float waI[KH8], wbI[KH8], waH[KH8], wbH[KH8];
#pragma unroll
    for (int kk = 0; kk < KH8; ++kk) {
        int k = kq * KH8 + kk;
        waI[kk] = wih[rowA * NH + k];
        wbI[kk] = wih[rowB * NH + k];
        waH[kk] = whh[rowA * NH + k];
        wbH[kk] = whh[rowB * NH + k];
    }
    if (tid < 64) {
        int gg = tid >> 4, jj = tid & 15, grow = gg * 256 + sl * SLU + jj;
        biasS[gg][jj] = bih[grow] + bhh[grow];
    }
    __syncthreads();

    const int fj = tid >> 3, fb = tid & 7;
    float c_reg = 0.f;
    const int fm = tid >> 4, fseg = tid & 15;
    const int ffo = sl * 10 + fm;                 // in [0,160)
    const int fo_o = ffo >> 3, fo_b = ffo & 7;

    for (int s = 0; s < TLEN; ++s) {
        // ---- phase A: NaN-wait h0[s] (slot (s+1)&7) — L0 runs ahead, usually ready
        const float* h0c = h0 + ((size_t)((s + 1) & 7) * NG + g) * GSLAB + tid;
        float xr0[8];
        for (;;) {
            bool bad = false;
#pragma unroll
            for (int i = 0; i < 8; ++i) { xr0[i] = HL(h0c + i * 256); if (xr0[i] != xr0[i]) bad = true; }
            if (__syncthreads_count(bad) == 0) break;
            __builtin_amdgcn_s_sleep(2);
        }
#pragma unroll
        for (int i = 0; i < 8; ++i) xs[i * 256 + tid] = xr0[i];
        __syncthreads();

        float4 aA0 = {0,0,0,0}, aA1 = {0,0,0,0}, aB0 = {0,0,0,0}, aB1 = {0,0,0,0};
        {
            const float* xsk = xs + (kq * KH8) * GS;
#pragma unroll
            for (int kk = 0; kk < KH8; ++kk) {
                float4 x0 = *(const float4*)(xsk + kk * GS);
                float4 x1 = *(const float4*)(xsk + kk * GS + 4);
                float wAv = waI[kk], wBv = wbI[kk];
                FMA4(aA0, x0, wAv); FMA4(aA1, x1, wAv);
                FMA4(aB0, x0, wBv); FMA4(aB1, x1, wBv);
            }
        }

        // ---- phase B: NaN-wait h1[s-1] (slot s&7) — overlapped by phase A above
        const float* h1p = h1 + ((size_t)(s & 7) * NG + g) * GSLAB + tid;
        float xr1[8];
        for (;;) {
            bool bad = false;
#pragma unroll
            for (int i = 0; i < 8; ++i) { xr1[i] = HL(h1p + i * 256); if (xr1[i] != xr1[i]) bad = true; }
            if (__syncthreads_count(bad) == 0) break;
            __builtin_amdgcn_s_sleep(2);
        }
#pragma unroll
        for (int i = 0; i < 8; ++i) xs[2048 + i * 256 + tid] = xr1[i];
        __syncthreads();

        {
            const float* xsk = xs + (NH + kq * KH8) * GS;
#pragma unroll
            for (int kk = 0; kk < KH8; ++kk) {
                float4 x0 = *(const float4*)(xsk + kk * GS);
                float4 x1 = *(const float4*)(xsk + kk * GS + 4);
                float wAv = waH[kk], wBv = wbH[kk];
                FMA4(aA0, x0, wAv); FMA4(aA1, x1, wAv);
                FMA4(aB0, x0, wBv); FMA4(aB1, x1, wBv);
            }
        }
        RED32(aA0); RED32(aA1); RED32(aB0); RED32(aB1);
        if ((tid & 32) == 0) {
            int gk = g4 * 4 + (tid >> 6);
            float4* r4 = (float4*)red;
            r4[gk * 32 + jp * 2 + 0]       = aA0;
            r4[gk * 32 + jp * 2 + 1]       = aA1;
            r4[gk * 32 + (jp + 8) * 2 + 0] = aB0;
            r4[gk * 32 + (jp + 8) * 2 + 1] = aB1;
        }
        __syncthreads();

        if (tid < 128) {
            float gate[4];
#pragma unroll
            for (int gg = 0; gg < 4; ++gg) {
                float s0 = 0.f;
#pragma unroll
                for (int k2 = 0; k2 < 4; ++k2)
                    s0 += red[(gg * 4 + k2) * 128 + fj * 8 + fb];
                gate[gg] = s0 + biasS[gg][fj];
            }
            float i_ = sigf(gate[0]), f_ = sigf(gate[1]);
            float g_ = tanh_f(gate[2]), o_ = sigf(gate[3]);
            c_reg = fmaf(f_, c_reg, i_ * g_);
            float h = o_ * tanh_f(c_reg);
            HS(&h1[((size_t)((s + 1) & 7) * NG + g) * GSLAB + sl * 128 + tid], h);
            // re-poison slot (s+5)&7 (= h1[s-4]); peers are lockstep +-1, safe
            HS(&h1[((size_t)((s + 5) & 7) * NG + g) * GSLAB + sl * 128 + tid], poison_f());
        }

        // FC for t = s-1 from staged h1prev (xs[2048..]); shuffle-reduce, no barrier
        if (s >= 1 && tid < 160) {
            const float* fwr = fcw + fo_o * NH;
            const float* xr = xs + NH * GS + fo_b;
            float p = 0.f;
#pragma unroll
            for (int i2 = 0; i2 < 16; ++i2) {
                int e = fseg * 16 + ((fseg + i2) & 15);   // bank rotation
                p = fmaf(fwr[e], xr[e * GS], p);
            }
#pragma unroll
            for (int d = 1; d < 16; d <<= 1) p += __shfl_xor(p, d, 16);
            if (fseg == 0)
                out[((size_t)(g * GS + fo_b) * NOUT + fo_o) * TLEN + (s - 1)] = p + fcb[fo_o];
        }
        __syncthreads();   // protect xs before next step's phase-A staging
    }

    // epilogue FC for t = TLEN-1: validate-load h1[TLEN-1] (slot 0)
    {
        const float* hlast = h1 + ((size_t)(TLEN & 7) * NG + g) * GSLAB + tid;
        float xr1[8];
        for (;;) {
            bool bad = false;
#pragma unroll
            for (int i = 0; i < 8; ++i) { xr1[i] = HL(hlast + i * 256); if (xr1[i] != xr1[i]) bad = true; }
            if (__syncthreads_count(bad) == 0) break;
            __builtin_amdgcn_s_sleep(2);
        }
#pragma unroll
        for (int i = 0; i < 8; ++i) xs[2048 + i * 256 + tid] = xr1[i];
        __syncthreads();
        if (tid < 160) {
            const float* fwr = fcw + fo_o * NH;
            const float* xr = xs + NH * GS + fo_b;
            float p = 0.f;
#pragma unroll
            for (int i2 = 0; i2 < 16; ++i2) {
                int e = fseg * 16 + ((fseg + i2) & 15);
                p = fmaf(fwr[e], xr[e * GS], p);
            }
#pragma unroll
            for (int d = 1; d < 16; d <<= 1) p += __shfl_xor(p, d, 16);
            if (fseg == 0)
                out[((size_t)(g * GS + fo_b) * NOUT + fo_o) * TLEN + (TLEN - 1)] = p + fcb[fo_o];
        }
    }
}

// Grid: 256 blocks x 256 threads, plain launch. Block (g, r): r<16 -> L0 slice r;
// r>=16 -> L1 slice r-16. launch_bounds(256,1): weights live in VGPRs (no spill).
__global__ __launch_bounds__(256, 1) void lstm_kernel(
    const float* __restrict__ feats,
    const float* __restrict__ wih0, const float* __restrict__ whh0,
    const float* __restrict__ bih0, const float* __restrict__ bhh0,
    const float* __restrict__ wih1, const float* __restrict__ whh1,
    const float* __restrict__ bih1, const float* __restrict__ bhh1,
    const float* __restrict__ fcw,  const float* __restrict__ fcb,
    float* h0h, float* h1h, float* __restrict__ out)
{
    __shared__ float xs[512 * GS];        // 16 KB
    __shared__ float red[16 * 128];       // 8 KB
    __shared__ float biasS[4][SLU];
    const int blk = blockIdx.x, tid = threadIdx.x;
    const int g = blk >> 5, r = blk & 31;

    if (r < 16)
        run_l0(g, r, tid, feats, wih0, whh0, bih0, bhh0,
               h0h, h1h, xs, red, biasS);
    else
        run_l1(g, r - 16, tid, h0h, wih1, whh1, bih1, bhh1,
               fcw, fcb, h1h, out, xs, red, biasS);
}

extern "C" void kernel_launch(void* const* d_in, const int* in_sizes, int n_in,
                              void* d_out, int out_size, void* d_ws, size_t ws_size,
                              hipStream_t stream) {
    (void)in_sizes; (void)n_in; (void)out_size; (void)ws_size;
    const float* x      = (const float*)d_in[0];
    const float* conv_w = (const float*)d_in[1];
    const float* conv_b = (const float*)d_in[2];
    const float* gamma  = (const float*)d_in[3];
    const float* beta   = (const float*)d_in[4];
    const float* wih0   = (const float*)d_in[5];
    const float* whh0   = (const float*)d_in[6];
    const float* bih0   = (const float*)d_in[7];
    const float* bhh0   = (const float*)d_in[8];
    const float* wih1   = (const float*)d_in[9];
    const float* whh1   = (const float*)d_in[10];
    const float* bih1   = (const float*)d_in[11];
    const float* bhh1   = (const float*)d_in[12];
    const float* fcw    = (const float*)d_in[13];
    const float* fcb    = (const float*)d_in[14];
    float* out = (float*)d_out;

    char* ws = (char*)d_ws;
    const size_t H_RING  = (size_t)NSLOT * NG * GSLAB * 4;       // 524,288 B each
    const size_t SLOT0_B = (size_t)NG * GSLAB * 4;               // 65,536 B
    const size_t FEATS_B = (size_t)TLEN * NG * NF * GS * 4;      // 33,554,432 B

    float* h0h      = (float*)(ws);
    float* h1h      = (float*)(ws + H_RING);
    float* feats    = (float*)(ws + 2 * H_RING);
    float* partials = (float*)(ws + 2 * H_RING + FEATS_B);

    // Poison rings with 0xFF (= NaN), then zero slot 0 (h[-1]).
    (void)hipMemsetAsync(h0h, 0xFF, H_RING, stream);
    (void)hipMemsetAsync(h1h, 0xFF, H_RING, stream);
    (void)hipMemsetAsync(h0h, 0x00, SLOT0_B, stream);
    (void)hipMemsetAsync(h1h, 0x00, SLOT0_B, stream);

    conv_stats_kernel<<<dim3(256), dim3(256), 0, stream>>>(x, conv_w, conv_b, partials);
    conv_bn_feats_kernel<<<dim3(2048), dim3(256), 0, stream>>>(
        x, conv_w, conv_b, gamma, beta, partials, feats);

    lstm_kernel<<<dim3(256), dim3(256), 0, stream>>>(
        feats, wih0, whh0, bih0, bhh0, wih1, whh1, bih1, bhh1,
        fcw, fcb, h0h, h1h, out);
}